// Round 11
// baseline (111.888 us; speedup 1.0000x reference)
//
#include <hip/hip_runtime.h>

#define N_NODES 10000
#define N_EDGES 320000
#define C_IN 128
#define C_OUT 128
#define KDIM 640            // 5 * 128

typedef __attribute__((ext_vector_type(8))) short short8;   // 8 bf16
typedef __attribute__((ext_vector_type(4))) float floatx4;  // MFMA C/D + nt loads
typedef __attribute__((ext_vector_type(2))) unsigned int uintx2;

// ---- bf16 helpers ---------------------------------------------------------
__device__ __forceinline__ unsigned short f2bf(float f) {
    unsigned int b = __float_as_uint(f);
    b = (b + 0x7FFFu + ((b >> 16) & 1u)) >> 16;   // RNE
    return (unsigned short)b;
}
__device__ __forceinline__ unsigned int pack2(float x, float y) {
    return (unsigned int)f2bf(x) | ((unsigned int)f2bf(y) << 16);
}
__device__ __forceinline__ float2 unpack2(unsigned int u) {
    float2 r;
    r.x = __uint_as_float(u << 16);
    r.y = __uint_as_float(u & 0xFFFF0000u);
    return r;
}

// ---------------------------------------------------------------------------
// Kernel 1 (prep): one launch, three block roles.
//   [0,1250)    : h (f32) -> hb (bf16). 2.56 MB -> fits 4 MB XCD-L2, halves
//                 gather bytes vs f32 (r10 FETCH showed f32 h re-fetched ~5x).
//   [1250,1330) : W -> Wt (128x640 bf16) transposed, ONCE (r10 paid 200 MB
//                 of L2 traffic re-converting per block).
//   [1330,1370) : CSR offsets via binary search over sorted src.
// ---------------------------------------------------------------------------
__global__ __launch_bounds__(256) void prep(
        const float* __restrict__ h, uintx2* __restrict__ hb4,
        const float* __restrict__ W, unsigned short* __restrict__ Wt,
        const int* __restrict__ src, int* __restrict__ offsets) {
    const int bid = blockIdx.x;
    const int tid = threadIdx.x;

    if (bid < 1250) {                       // conv_h: 1250*256 = 320000 exact
        const int t = bid * 256 + tid;
        floatx4 v = __builtin_nontemporal_load(&((const floatx4*)h)[t]);
        uintx2 o;
        o.x = pack2(v.x, v.y);
        o.y = pack2(v.z, v.w);
        hb4[t] = o;                         // cached: want hb4 L2-resident
    } else if (bid < 1330) {                // conv_w transpose, 80 blocks
        __shared__ float tile[32][33];
        const int b = bid - 1250;
        const int k0 = (b % 20) * 32, o0 = (b / 20) * 32;
        const int tx = tid & 31, ty = tid >> 5;      // 32 x 8
#pragma unroll
        for (int i = 0; i < 4; ++i)
            tile[ty + 8 * i][tx] =
                __builtin_nontemporal_load(&W[(size_t)(k0 + ty + 8 * i) * C_OUT + o0 + tx]);
        __syncthreads();
#pragma unroll
        for (int i = 0; i < 4; ++i)
            Wt[(size_t)(o0 + ty + 8 * i) * KDIM + k0 + tx] = f2bf(tile[tx][ty + 8 * i]);
    } else {                                // offsets, 40 blocks
        const int n = (bid - 1330) * 256 + tid;
        if (n > N_NODES) return;
        int lo = 0, hi = N_EDGES;
        while (lo < hi) {
            int mid = (lo + hi) >> 1;
            if (src[mid] < n) lo = mid + 1; else hi = mid;
        }
        offsets[n] = lo;
    }
}

// ---------------------------------------------------------------------------
// Kernel 2 (scatter): ONE NODE PER WAVE, 2500 blocks x 256 thr (4 waves).
//   ZERO LDS, no barriers -> ~9.8 blocks/CU, occupancy capped only by the
//   32-wave/CU limit (r10 measured 38% occupancy at 625 blocks; the grid,
//   not resources, was the cap). 3x the waves to hide the s_load->gather
//   latency chain that dominates this phase.
//   Scalar metadata (r8 structure): node is wave-uniform -> e0/e1, dst[e],
//   X[e][*] all come via s_load on the SMEM pipe. Lane l = channels
//   {2l,2l+1} as one uint (2 bf16); gather = 256 B/wave/edge, coalesced.
//   Unroll 8 -> 8 independent gathers in flight. R written bf16 to ws.
// ---------------------------------------------------------------------------
__global__ __launch_bounds__(256) void scatter(
        const unsigned int* __restrict__ h2,   // (10000, 64) uint = 2 bf16 ch
        const float* __restrict__ X,           // (320000, 5)
        const int* __restrict__ dst,
        const int* __restrict__ offsets,
        unsigned int* __restrict__ R2) {       // (10000, 320) uint = bf16 pairs
    const int wv   = __builtin_amdgcn_readfirstlane(threadIdx.x >> 6);
    const int lane = threadIdx.x & 63;
    const int node = blockIdx.x * 4 + wv;      // 2500*4 = 10000 exact

    const int e0 = offsets[node];              // s_load (node scalar)
    const int e1 = offsets[node + 1];

    float a0x=0,a0y=0, a1x=0,a1y=0, a2x=0,a2y=0, a3x=0,a3y=0, a4x=0,a4y=0;

    int e = e0;
    for (; e + 7 < e1; e += 8) {               // scalar loop, unroll 8
        int d[8];
        unsigned int u[8];
#pragma unroll
        for (int q = 0; q < 8; ++q) d[q] = dst[e + q];        // s_loads
#pragma unroll
        for (int q = 0; q < 8; ++q)
            u[q] = h2[(size_t)d[q] * 64 + lane];              // 8 gathers in flight
#pragma unroll
        for (int q = 0; q < 8; ++q) {
            const float* Xp = X + (size_t)(e + q) * 5;        // s_loads
            const float x0 = Xp[0], x1 = Xp[1], x2 = Xp[2], x3 = Xp[3], x4 = Xp[4];
            const float2 hv = unpack2(u[q]);
            a0x = fmaf(x0, hv.x, a0x); a0y = fmaf(x0, hv.y, a0y);
            a1x = fmaf(x1, hv.x, a1x); a1y = fmaf(x1, hv.y, a1y);
            a2x = fmaf(x2, hv.x, a2x); a2y = fmaf(x2, hv.y, a2y);
            a3x = fmaf(x3, hv.x, a3x); a3y = fmaf(x3, hv.y, a3y);
            a4x = fmaf(x4, hv.x, a4x); a4y = fmaf(x4, hv.y, a4y);
        }
    }
    for (; e < e1; ++e) {                      // scalar tail
        const int d = dst[e];
        const unsigned int u = h2[(size_t)d * 64 + lane];
        const float* Xp = X + (size_t)e * 5;
        const float x0 = Xp[0], x1 = Xp[1], x2 = Xp[2], x3 = Xp[3], x4 = Xp[4];
        const float2 hv = unpack2(u);
        a0x = fmaf(x0, hv.x, a0x); a0y = fmaf(x0, hv.y, a0y);
        a1x = fmaf(x1, hv.x, a1x); a1y = fmaf(x1, hv.y, a1y);
        a2x = fmaf(x2, hv.x, a2x); a2y = fmaf(x2, hv.y, a2y);
        a3x = fmaf(x3, hv.x, a3x); a3y = fmaf(x3, hv.y, a3y);
        a4x = fmaf(x4, hv.x, a4x); a4y = fmaf(x4, hv.y, a4y);
    }

    // R row: uint index = node*320 + kk*64 + lane  (short offset kk*128+2l)
    unsigned int* Rn = R2 + (size_t)node * 320;
    Rn[0 * 64 + lane] = pack2(a0x, a0y);
    Rn[1 * 64 + lane] = pack2(a1x, a1y);
    Rn[2 * 64 + lane] = pack2(a2x, a2y);
    Rn[3 * 64 + lane] = pack2(a3x, a3y);
    Rn[4 * 64 + lane] = pack2(a4x, a4y);
}

// ---------------------------------------------------------------------------
// Kernel 3 (gemm): out(10000x128) = R(10000x640)bf16 x Wt(128x640)^T + bias.
//   157 blocks x 256 thr (4 waves), 64-row tiles. Per 64-k chunk: As+Bs
//   staged coalesced (b128), pitch 66 shorts = 33 dwords (odd) -> <=2-way
//   banks. Per wave: 16 rows x 128 cols = 8 acc tiles, 160 MFMA total.
//   D layout row=quad*4+r, col=lane&15 (verified rounds 3-10).
// ---------------------------------------------------------------------------
__global__ __launch_bounds__(256) void gemm(
        const unsigned short* __restrict__ R,
        const unsigned short* __restrict__ Wt,
        const float* __restrict__ bias,
        float* __restrict__ out) {
    __shared__ unsigned short As[64][66];      // 8.4 KB
    __shared__ unsigned short Bs[128][66];     // 16.9 KB

    const int tid  = threadIdx.x;
    const int wv   = tid >> 6;
    const int lane = tid & 63;
    const int col  = lane & 15;
    const int quad = lane >> 4;
    const int m0   = blockIdx.x * 64;          // 157*64 = 10048 (mask at store)

    floatx4 acc[8];
#pragma unroll
    for (int t = 0; t < 8; ++t) acc[t] = (floatx4){0.f, 0.f, 0.f, 0.f};

    for (int chunk = 0; chunk < 10; ++chunk) {
        if (chunk) __syncthreads();
        // As: 64 rows x 64 bf16 = 512 b128 chunks, 2/thread, coalesced.
        // Rows >= 10000 read ws garbage beyond R -- in-bounds of ws, masked
        // at the store.
#pragma unroll
        for (int r = 0; r < 2; ++r) {
            const int c = r * 256 + tid;
            const int row = c >> 3, c8 = c & 7;
            *(short8*)&As[row][c8 * 8] =
                *(const short8*)(R + (size_t)(m0 + row) * KDIM + chunk * 64 + c8 * 8);
        }
        // Bs: 128 rows x 64 bf16 = 1024 b128 chunks, 4/thread, coalesced.
#pragma unroll
        for (int r = 0; r < 4; ++r) {
            const int c = r * 256 + tid;
            const int row = c >> 3, c8 = c & 7;
            *(short8*)&Bs[row][c8 * 8] =
                *(const short8*)(Wt + (size_t)row * KDIM + chunk * 64 + c8 * 8);
        }
        __syncthreads();

#pragma unroll
        for (int hh = 0; hh < 2; ++hh) {
            const short8 af = *(const short8*)&As[wv * 16 + col][hh * 32 + quad * 8];
#pragma unroll
            for (int t = 0; t < 8; ++t) {
                const short8 bf = *(const short8*)&Bs[t * 16 + col][hh * 32 + quad * 8];
                acc[t] = __builtin_amdgcn_mfma_f32_16x16x32_bf16(af, bf, acc[t], 0, 0, 0);
            }
        }
    }

#pragma unroll
    for (int t = 0; t < 8; ++t) {
        const float bv = bias[t * 16 + col];
#pragma unroll
        for (int r = 0; r < 4; ++r) {
            const int m = m0 + wv * 16 + quad * 4 + r;
            if (m < N_NODES)
                __builtin_nontemporal_store(acc[t][r] + bv,
                                            &out[(size_t)m * C_OUT + t * 16 + col]);
        }
    }
}

// ---------------------------------------------------------------------------
extern "C" void kernel_launch(void* const* d_in, const int* in_sizes, int n_in,
                              void* d_out, int out_size, void* d_ws, size_t ws_size,
                              hipStream_t stream) {
    const float* h      = (const float*)d_in[0];   // (10000,128)
    const float* X      = (const float*)d_in[1];   // (320000,5)
    const int*   ei     = (const int*)d_in[2];     // (2,320000)
    const float* weight = (const float*)d_in[4];   // (5,128,128) == W(640,128)
    const float* bias   = (const float*)d_in[5];   // (128,)
    float* out = (float*)d_out;

    const int* src = ei;
    const int* dst = ei + N_EDGES;

    // Workspace: offsets [0,64KB) | hb bf16 [64KB,+2.56MB) | Wt bf16 [+4MB)
    //            | R bf16 [+8MB, +20.8MB)
    char* wsb = (char*)d_ws;
    int*            offsets = (int*)wsb;
    uintx2*         hb4     = (uintx2*)(wsb + (64 << 10));
    unsigned short* Wtb     = (unsigned short*)(wsb + (64 << 10) + (4 << 20));
    unsigned int*   R2      = (unsigned int*)(wsb + (64 << 10) + (8 << 20));

    prep<<<1370, 256, 0, stream>>>(h, hb4, weight, Wtb, src, offsets);
    scatter<<<2500, 256, 0, stream>>>((const unsigned int*)hb4, X, dst, offsets, R2);
    gemm<<<157, 256, 0, stream>>>((const unsigned short*)R2, Wtb, bias, out);
}